// Round 2
// baseline (2050.874 us; speedup 1.0000x reference)
//
#include <hip/hip_runtime.h>
#include <hip/hip_bf16.h>

typedef short short8 __attribute__((ext_vector_type(8)));
typedef float floatx4 __attribute__((ext_vector_type(4)));
using bf16 = __hip_bfloat16;

static constexpr int L = 2048, H = 2048, D = 4096, NS = 16, R = 128, KC = 4;

// ---------------- elementwise fp32 -> bf16 cast ----------------
__global__ void cast_f2b(const float* __restrict__ in, bf16* __restrict__ out, int n) {
  int i = blockIdx.x * 256 + threadIdx.x;
  if (i < n) out[i] = __float2bfloat16(in[i]);
}

// ------------- weight transpose+cast (fp32 [Rr,Cc] -> bf16 [Cc,Rr]) -------------
__global__ void transpose_cast(const float* __restrict__ in, bf16* __restrict__ out,
                               int Rr, int Cc) {
  __shared__ float tile[32][33];
  int c0 = blockIdx.x * 32, r0 = blockIdx.y * 32;
  int tx = threadIdx.x, ty = threadIdx.y;  // 32 x 8
#pragma unroll
  for (int i = 0; i < 32; i += 8)
    tile[ty + i][tx] = in[(size_t)(r0 + ty + i) * Cc + (c0 + tx)];
  __syncthreads();
#pragma unroll
  for (int i = 0; i < 32; i += 8)
    out[(size_t)(c0 + ty + i) * Rr + (r0 + tx)] = __float2bfloat16(tile[tx][ty + i]);
}

// ---------------- bf16 MFMA GEMM: C[M,N] = A[M,K] * Bt[N,K]^T ----------------
// 128x128 tile, 4 waves (2x2), each wave 64x64 = 4x4 of 16x16x32 MFMA.
// LDS rows padded to 40 shorts (stride 80B = 20 banks -> only free 2-way aliasing).
template <bool OUT_BF16, bool N_GUARD>
__global__ __launch_bounds__(256) void gemm_bt(
    const bf16* __restrict__ A, int lda,
    const bf16* __restrict__ Bt, int ldb,
    void* __restrict__ Cptr, int ldc,
    int N, int K) {
  __shared__ short As[128 * 40];
  __shared__ short Bs[128 * 40];
  const int m0 = blockIdx.y * 128, n0 = blockIdx.x * 128;
  const int tid = threadIdx.x;
  const int lane = tid & 63;
  const int wave = tid >> 6;
  const int wm = (wave >> 1) * 64, wn = (wave & 1) * 64;
  const int lr = lane & 15, kq = lane >> 4;
  const int srow = tid >> 2, scol = (tid & 3) * 8;  // 4 threads/row, 8 bf16 each

  floatx4 acc[4][4];
#pragma unroll
  for (int i = 0; i < 4; i++)
#pragma unroll
    for (int j = 0; j < 4; j++)
#pragma unroll
      for (int r = 0; r < 4; r++) acc[i][j][r] = 0.f;

  for (int k0 = 0; k0 < K; k0 += 32) {
    __syncthreads();
#pragma unroll
    for (int h = 0; h < 2; h++) {
      int r = srow + h * 64;
      short8 va = *(const short8*)((const short*)A + (size_t)(m0 + r) * lda + k0 + scol);
      *(short8*)(&As[r * 40 + scol]) = va;
    }
#pragma unroll
    for (int h = 0; h < 2; h++) {
      int r = srow + h * 64;
      short8 vb;
      if (!N_GUARD || (n0 + r) < N) {
        vb = *(const short8*)((const short*)Bt + (size_t)(n0 + r) * ldb + k0 + scol);
      } else {
#pragma unroll
        for (int q = 0; q < 8; q++) vb[q] = 0;
      }
      *(short8*)(&Bs[r * 40 + scol]) = vb;
    }
    __syncthreads();
    short8 af[4], bfr[4];
#pragma unroll
    for (int i = 0; i < 4; i++)
      af[i] = *(const short8*)(&As[(wm + i * 16 + lr) * 40 + kq * 8]);
#pragma unroll
    for (int j = 0; j < 4; j++)
      bfr[j] = *(const short8*)(&Bs[(wn + j * 16 + lr) * 40 + kq * 8]);
#pragma unroll
    for (int i = 0; i < 4; i++)
#pragma unroll
      for (int j = 0; j < 4; j++)
        acc[i][j] = __builtin_amdgcn_mfma_f32_16x16x32_bf16(af[i], bfr[j], acc[i][j], 0, 0, 0);
  }

  const int rb = kq * 4;  // C/D: col = lane&15, row = (lane>>4)*4 + reg  [m89/m91]
#pragma unroll
  for (int i = 0; i < 4; i++) {
#pragma unroll
    for (int j = 0; j < 4; j++) {
      int col = n0 + wn + j * 16 + lr;
      if (N_GUARD && col >= N) continue;
      int row = m0 + wm + i * 16 + rb;
#pragma unroll
      for (int r = 0; r < 4; r++) {
        float v = acc[i][j][r];
        if (OUT_BF16)
          ((bf16*)Cptr)[(size_t)(row + r) * ldc + col] = __float2bfloat16(v);
        else
          ((float*)Cptr)[(size_t)(row + r) * ldc + col] = v;
      }
    }
  }
}

// ---------------- causal depthwise conv (K=4) + bias + SiLU ----------------
__global__ void conv_silu(const float* __restrict__ proj,
                          const float* __restrict__ conv_w, const float* __restrict__ conv_b,
                          float* __restrict__ hs_f, bf16* __restrict__ hs_b) {
  int idx = blockIdx.x * 256 + threadIdx.x;  // t*D + d
  int d = idx & (D - 1), t = idx >> 12;
  float acc = conv_b[d];
#pragma unroll
  for (int k = 0; k < KC; k++) {
    int tt = t + k - (KC - 1);
    if (tt >= 0) acc += proj[(size_t)tt * (2 * D) + d] * conv_w[k * D + d];
  }
  float s = acc / (1.f + __expf(-acc));
  hs_f[idx] = s;
  hs_b[idx] = __float2bfloat16(s);
}

// ---------------- cast dt_in (first 128 cols of ssm_p) to bf16 ----------------
__global__ void dtin_cast(const float* __restrict__ ssmp, bf16* __restrict__ dtin) {
  int idx = blockIdx.x * 256 + threadIdx.x;  // t*R + r
  int r = idx & (R - 1), t = idx >> 7;
  dtin[idx] = __float2bfloat16(ssmp[(size_t)t * 160 + r]);
}

// ---------------- dt = softplus(dt_pre + b_dt) ----------------
__global__ void dt_softplus(float* __restrict__ dtbuf, const float* __restrict__ b_dt) {
  int idx = blockIdx.x * 256 + threadIdx.x;
  int d = idx & (D - 1);
  float v = dtbuf[idx] + b_dt[d];
  dtbuf[idx] = (v > 20.f) ? v : log1pf(__expf(v));
}

// ---------------- selective scan, fused epilogue ----------------
// one lane per (d,n); 16-lane shuffle reduction over n gives y[t,d]
__global__ __launch_bounds__(256) void scan_fused(
    const float* __restrict__ dtb, const float* __restrict__ hs_f,
    const float* __restrict__ ssmp, const float* __restrict__ proj,
    const float* __restrict__ A_log, const float* __restrict__ D_param,
    bf16* __restrict__ y_b) {
  int g = blockIdx.x * 256 + threadIdx.x;
  int d = g >> 4, n = g & 15;
  float Acoef = -__expf(A_log[d * NS + n]);
  float Dp = D_param[d];
  float s = 0.f;
#pragma unroll 2
  for (int t = 0; t < L; t++) {
    float dtv = dtb[(size_t)t * D + d];
    float hsv = hs_f[(size_t)t * D + d];
    float bv = ssmp[(size_t)t * 160 + 128 + n];
    float cv = ssmp[(size_t)t * 160 + 144 + n];
    float dA = __expf(dtv * Acoef);
    s = dA * s + dtv * bv * hsv;
    float p = s * cv;
    p += __shfl_xor(p, 1, 16);
    p += __shfl_xor(p, 2, 16);
    p += __shfl_xor(p, 4, 16);
    p += __shfl_xor(p, 8, 16);
    if (n == 0) {
      float gv = proj[(size_t)t * (2 * D) + D + d];
      float yv = (p + hsv * Dp) * (gv / (1.f + __expf(-gv)));
      y_b[(size_t)t * D + d] = __float2bfloat16(yv);
    }
  }
}

extern "C" void kernel_launch(void* const* d_in, const int* in_sizes, int n_in,
                              void* d_out, int out_size, void* d_ws, size_t ws_size,
                              hipStream_t stream) {
  const float* x      = (const float*)d_in[0];
  const float* W_in   = (const float*)d_in[1];
  const float* conv_w = (const float*)d_in[2];
  const float* conv_b = (const float*)d_in[3];
  const float* W_x    = (const float*)d_in[4];
  const float* W_dt   = (const float*)d_in[5];
  const float* b_dt   = (const float*)d_in[6];
  const float* A_log  = (const float*)d_in[7];
  const float* D_par  = (const float*)d_in[8];
  const float* W_out  = (const float*)d_in[9];
  float* outp = (float*)d_out;

  char* ws = (char*)d_ws;
  size_t off = 0;
  auto alloc = [&](size_t bytes) {
    char* p = ws + off;
    off += (bytes + 255) & ~(size_t)255;
    return (void*)p;
  };
  float* proj   = (float*)alloc((size_t)L * 2 * D * 4);   // 64 MB
  float* hs_f   = (float*)alloc((size_t)L * D * 4);       // 32 MB
  bf16*  hs_b   = (bf16*) alloc((size_t)L * D * 2);       // 16 MB
  float* ssmp   = (float*)alloc((size_t)L * 160 * 4);     // 1.25 MB
  bf16*  dtin_b = (bf16*) alloc((size_t)L * R * 2);       // 0.5 MB
  float* dtbuf  = (float*)alloc((size_t)L * D * 4);       // 32 MB
  bf16*  y_b    = (bf16*) alloc((size_t)L * D * 2);       // 16 MB
  bf16*  x_b    = (bf16*) alloc((size_t)L * H * 2);       // 8 MB
  bf16*  WinT   = (bf16*) alloc((size_t)2 * D * H * 2);   // 32 MB  [2D, H]
  bf16*  WoutT  = (bf16*) alloc((size_t)H * D * 2);       // 16 MB  [H, D]
  bf16*  WxT    = (bf16*) alloc((size_t)160 * D * 2);     // 1.25 MB [160, D]
  bf16*  WdtT   = (bf16*) alloc((size_t)D * R * 2);       // 1 MB   [D, R]

  cast_f2b<<<(L * H) / 256, 256, 0, stream>>>(x, x_b, L * H);

  dim3 tb(32, 8);
  transpose_cast<<<dim3((2 * D) / 32, H / 32), tb, 0, stream>>>(W_in, WinT, H, 2 * D);
  transpose_cast<<<dim3(H / 32, D / 32), tb, 0, stream>>>(W_out, WoutT, D, H);
  transpose_cast<<<dim3(160 / 32, D / 32), tb, 0, stream>>>(W_x, WxT, D, 160);
  transpose_cast<<<dim3(D / 32, R / 32), tb, 0, stream>>>(W_dt, WdtT, R, D);

  // proj = x @ W_in   [L, 2D] fp32
  gemm_bt<false, false><<<dim3((2 * D) / 128, L / 128), 256, 0, stream>>>(
      x_b, H, WinT, H, proj, 2 * D, 2 * D, H);
  // hs = silu(conv(proj[:, :D]))
  conv_silu<<<(L * D) / 256, 256, 0, stream>>>(proj, conv_w, conv_b, hs_f, hs_b);
  // ssm_p = hs @ W_x   [L, 160] fp32
  gemm_bt<false, true><<<dim3(2, L / 128), 256, 0, stream>>>(
      hs_b, D, WxT, D, ssmp, 160, 160, D);
  dtin_cast<<<(L * R) / 256, 256, 0, stream>>>(ssmp, dtin_b);
  // dt_pre = dt_in @ W_dt   [L, D] fp32
  gemm_bt<false, false><<<dim3(D / 128, L / 128), 256, 0, stream>>>(
      dtin_b, R, WdtT, R, dtbuf, D, D, R);
  dt_softplus<<<(L * D) / 256, 256, 0, stream>>>(dtbuf, b_dt);
  // scan + epilogue -> y (bf16)
  scan_fused<<<(D * NS) / 256, 256, 0, stream>>>(dtbuf, hs_f, ssmp, proj, A_log, D_par, y_b);
  // out = y @ W_out   [L, H] fp32
  gemm_bt<false, false><<<dim3(H / 128, L / 128), 256, 0, stream>>>(
      y_b, D, WoutT, D, outp, H, H, D);
}

// Round 3
// 648.213 us; speedup vs baseline: 3.1639x; 3.1639x over previous
//
#include <hip/hip_runtime.h>
#include <hip/hip_bf16.h>

typedef short short8 __attribute__((ext_vector_type(8)));
typedef float floatx4 __attribute__((ext_vector_type(4)));
using bf16 = __hip_bfloat16;

static constexpr int L = 2048, H = 2048, D = 4096, NS = 16, R = 128, KC = 4;
static constexpr int CCH = 64, TCH = L / CCH;  // 64 chunks x 32 steps

// ---------------- elementwise fp32 -> bf16 cast ----------------
__global__ void cast_f2b(const float* __restrict__ in, bf16* __restrict__ out, int n) {
  int i = blockIdx.x * 256 + threadIdx.x;
  if (i < n) out[i] = __float2bfloat16(in[i]);
}

// ------------- weight transpose+cast (fp32 [Rr,Cc] -> bf16 [Cc,Rr]) -------------
__global__ void transpose_cast(const float* __restrict__ in, bf16* __restrict__ out,
                               int Rr, int Cc) {
  __shared__ float tile[32][33];
  int c0 = blockIdx.x * 32, r0 = blockIdx.y * 32;
  int tx = threadIdx.x, ty = threadIdx.y;  // 32 x 8
#pragma unroll
  for (int i = 0; i < 32; i += 8)
    tile[ty + i][tx] = in[(size_t)(r0 + ty + i) * Cc + (c0 + tx)];
  __syncthreads();
#pragma unroll
  for (int i = 0; i < 32; i += 8)
    out[(size_t)(c0 + ty + i) * Rr + (r0 + tx)] = __float2bfloat16(tile[tx][ty + i]);
}

// ---------------- bf16 MFMA GEMM: C[M,N] = A[M,K] * Bt[N,K]^T ----------------
template <bool OUT_BF16, bool N_GUARD>
__global__ __launch_bounds__(256) void gemm_bt(
    const bf16* __restrict__ A, int lda,
    const bf16* __restrict__ Bt, int ldb,
    void* __restrict__ Cptr, int ldc,
    int N, int K) {
  __shared__ short As[128 * 40];
  __shared__ short Bs[128 * 40];
  const int m0 = blockIdx.y * 128, n0 = blockIdx.x * 128;
  const int tid = threadIdx.x;
  const int lane = tid & 63;
  const int wave = tid >> 6;
  const int wm = (wave >> 1) * 64, wn = (wave & 1) * 64;
  const int lr = lane & 15, kq = lane >> 4;
  const int srow = tid >> 2, scol = (tid & 3) * 8;

  floatx4 acc[4][4];
#pragma unroll
  for (int i = 0; i < 4; i++)
#pragma unroll
    for (int j = 0; j < 4; j++)
#pragma unroll
      for (int r = 0; r < 4; r++) acc[i][j][r] = 0.f;

  for (int k0 = 0; k0 < K; k0 += 32) {
    __syncthreads();
#pragma unroll
    for (int h = 0; h < 2; h++) {
      int r = srow + h * 64;
      short8 va = *(const short8*)((const short*)A + (size_t)(m0 + r) * lda + k0 + scol);
      *(short8*)(&As[r * 40 + scol]) = va;
    }
#pragma unroll
    for (int h = 0; h < 2; h++) {
      int r = srow + h * 64;
      short8 vb;
      if (!N_GUARD || (n0 + r) < N) {
        vb = *(const short8*)((const short*)Bt + (size_t)(n0 + r) * ldb + k0 + scol);
      } else {
#pragma unroll
        for (int q = 0; q < 8; q++) vb[q] = 0;
      }
      *(short8*)(&Bs[r * 40 + scol]) = vb;
    }
    __syncthreads();
    short8 af[4], bfr[4];
#pragma unroll
    for (int i = 0; i < 4; i++)
      af[i] = *(const short8*)(&As[(wm + i * 16 + lr) * 40 + kq * 8]);
#pragma unroll
    for (int j = 0; j < 4; j++)
      bfr[j] = *(const short8*)(&Bs[(wn + j * 16 + lr) * 40 + kq * 8]);
#pragma unroll
    for (int i = 0; i < 4; i++)
#pragma unroll
      for (int j = 0; j < 4; j++)
        acc[i][j] = __builtin_amdgcn_mfma_f32_16x16x32_bf16(af[i], bfr[j], acc[i][j], 0, 0, 0);
  }

  const int rb = kq * 4;
#pragma unroll
  for (int i = 0; i < 4; i++) {
#pragma unroll
    for (int j = 0; j < 4; j++) {
      int col = n0 + wn + j * 16 + lr;
      if (N_GUARD && col >= N) continue;
      int row = m0 + wm + i * 16 + rb;
#pragma unroll
      for (int r = 0; r < 4; r++) {
        float v = acc[i][j][r];
        if (OUT_BF16)
          ((bf16*)Cptr)[(size_t)(row + r) * ldc + col] = __float2bfloat16(v);
        else
          ((float*)Cptr)[(size_t)(row + r) * ldc + col] = v;
      }
    }
  }
}

// ---------------- causal depthwise conv (K=4) + bias + SiLU ----------------
__global__ void conv_silu(const float* __restrict__ proj,
                          const float* __restrict__ conv_w, const float* __restrict__ conv_b,
                          float* __restrict__ hs_f, bf16* __restrict__ hs_b) {
  int idx = blockIdx.x * 256 + threadIdx.x;  // t*D + d
  int d = idx & (D - 1), t = idx >> 12;
  float acc = conv_b[d];
#pragma unroll
  for (int k = 0; k < KC; k++) {
    int tt = t + k - (KC - 1);
    if (tt >= 0) acc += proj[(size_t)tt * (2 * D) + d] * conv_w[k * D + d];
  }
  float s = acc / (1.f + __expf(-acc));
  hs_f[idx] = s;
  hs_b[idx] = __float2bfloat16(s);
}

// ---------------- cast dt_in (first 128 cols of ssm_p) to bf16 ----------------
__global__ void dtin_cast(const float* __restrict__ ssmp, bf16* __restrict__ dtin) {
  int idx = blockIdx.x * 256 + threadIdx.x;  // t*R + r
  int r = idx & (R - 1), t = idx >> 7;
  dtin[idx] = __float2bfloat16(ssmp[(size_t)t * 160 + r]);
}

__device__ __forceinline__ float softplusf(float v) {
  return (v > 20.f) ? v : log1pf(__expf(v));
}

// ---------------- scan phase 1: per-chunk local scan ----------------
// lane = one d; 16 n-states in registers. Outputs sum(dt) and local final state.
__global__ __launch_bounds__(256) void scan_phase1(
    const float* __restrict__ dtraw, const float* __restrict__ b_dt,
    const float* __restrict__ hs_f, const float* __restrict__ ssmp,
    const float* __restrict__ A_log,
    float* __restrict__ sdt_out, float* __restrict__ S_out) {
  const int d = blockIdx.x * 256 + threadIdx.x;
  const int c = blockIdx.y;
  float An[NS];
#pragma unroll
  for (int n = 0; n < NS; n++) An[n] = -__expf(A_log[d * NS + n]);
  const float bdt = b_dt[d];
  float s[NS];
#pragma unroll
  for (int n = 0; n < NS; n++) s[n] = 0.f;
  float sdt = 0.f;
  const int t0 = c * TCH;
#pragma unroll 2
  for (int t = t0; t < t0 + TCH; t++) {
    float dtv = softplusf(dtraw[(size_t)t * D + d] + bdt);
    float hsv = hs_f[(size_t)t * D + d];
    sdt += dtv;
    float u = dtv * hsv;
    const float* Bp = ssmp + (size_t)t * 160 + 128;
#pragma unroll
    for (int n = 0; n < NS; n++) {
      float dA = __expf(An[n] * dtv);
      s[n] = dA * s[n] + Bp[n] * u;
    }
  }
  sdt_out[(size_t)c * D + d] = sdt;
  float* Sp = S_out + ((size_t)c * D + d) * NS;
#pragma unroll
  for (int n = 0; n < NS; n += 4)
    *(floatx4*)(Sp + n) = *(floatx4*)(s + n);
}

// ---------------- scan phase 2: sequential combine over chunks ----------------
__global__ __launch_bounds__(256) void scan_phase2(
    const float* __restrict__ sdt, const float* __restrict__ S,
    const float* __restrict__ A_log, float* __restrict__ I) {
  int g = blockIdx.x * 256 + threadIdx.x;  // d*16 + n
  int d = g >> 4;
  float An = -__expf(A_log[g]);
  float cur = 0.f;
  for (int c = 0; c < CCH; c++) {
    I[(size_t)c * D * NS + g] = cur;
    cur = __expf(An * sdt[(size_t)c * D + d]) * cur + S[(size_t)c * D * NS + g];
  }
}

// ---------------- scan phase 3: seeded per-chunk scan + fused epilogue ----------------
__global__ __launch_bounds__(256) void scan_phase3(
    const float* __restrict__ dtraw, const float* __restrict__ b_dt,
    const float* __restrict__ hs_f, const float* __restrict__ ssmp,
    const float* __restrict__ proj, const float* __restrict__ A_log,
    const float* __restrict__ D_param, const float* __restrict__ I,
    bf16* __restrict__ y_b) {
  const int d = blockIdx.x * 256 + threadIdx.x;
  const int c = blockIdx.y;
  float An[NS];
#pragma unroll
  for (int n = 0; n < NS; n++) An[n] = -__expf(A_log[d * NS + n]);
  const float bdt = b_dt[d];
  const float Dp = D_param[d];
  float s[NS];
  const float* Ip = I + ((size_t)c * D + d) * NS;
#pragma unroll
  for (int n = 0; n < NS; n += 4)
    *(floatx4*)(s + n) = *(const floatx4*)(Ip + n);
  const int t0 = c * TCH;
#pragma unroll 2
  for (int t = t0; t < t0 + TCH; t++) {
    float dtv = softplusf(dtraw[(size_t)t * D + d] + bdt);
    float hsv = hs_f[(size_t)t * D + d];
    float u = dtv * hsv;
    const float* Bp = ssmp + (size_t)t * 160 + 128;
    const float* Cp = ssmp + (size_t)t * 160 + 144;
    float y = 0.f;
#pragma unroll
    for (int n = 0; n < NS; n++) {
      float dA = __expf(An[n] * dtv);
      s[n] = dA * s[n] + Bp[n] * u;
      y += s[n] * Cp[n];
    }
    float gv = proj[(size_t)t * (2 * D) + D + d];
    float yv = (y + hsv * Dp) * (gv / (1.f + __expf(-gv)));
    y_b[(size_t)t * D + d] = __float2bfloat16(yv);
  }
}

extern "C" void kernel_launch(void* const* d_in, const int* in_sizes, int n_in,
                              void* d_out, int out_size, void* d_ws, size_t ws_size,
                              hipStream_t stream) {
  const float* x      = (const float*)d_in[0];
  const float* W_in   = (const float*)d_in[1];
  const float* conv_w = (const float*)d_in[2];
  const float* conv_b = (const float*)d_in[3];
  const float* W_x    = (const float*)d_in[4];
  const float* W_dt   = (const float*)d_in[5];
  const float* b_dt   = (const float*)d_in[6];
  const float* A_log  = (const float*)d_in[7];
  const float* D_par  = (const float*)d_in[8];
  const float* W_out  = (const float*)d_in[9];
  float* outp = (float*)d_out;

  char* ws = (char*)d_ws;
  size_t off = 0;
  auto alloc = [&](size_t bytes) {
    char* p = ws + off;
    off += (bytes + 255) & ~(size_t)255;
    return (void*)p;
  };
  float* proj   = (float*)alloc((size_t)L * 2 * D * 4);     // 64 MB
  float* hs_f   = (float*)alloc((size_t)L * D * 4);         // 32 MB
  bf16*  hs_b   = (bf16*) alloc((size_t)L * D * 2);         // 16 MB
  float* ssmp   = (float*)alloc((size_t)L * 160 * 4);       // 1.25 MB
  bf16*  dtin_b = (bf16*) alloc((size_t)L * R * 2);         // 0.5 MB
  float* dtbuf  = (float*)alloc((size_t)L * D * 4);         // 32 MB (raw dt_pre)
  bf16*  y_b    = (bf16*) alloc((size_t)L * D * 2);         // 16 MB
  bf16*  x_b    = (bf16*) alloc((size_t)L * H * 2);         // 8 MB
  bf16*  WinT   = (bf16*) alloc((size_t)2 * D * H * 2);     // 32 MB
  bf16*  WoutT  = (bf16*) alloc((size_t)H * D * 2);         // 16 MB
  bf16*  WxT    = (bf16*) alloc((size_t)160 * D * 2);       // 1.25 MB
  bf16*  WdtT   = (bf16*) alloc((size_t)D * R * 2);         // 1 MB
  float* sdt    = (float*)alloc((size_t)CCH * D * 4);       // 1 MB
  float* Sbuf   = (float*)alloc((size_t)CCH * D * NS * 4);  // 16 MB
  float* Ibuf   = (float*)alloc((size_t)CCH * D * NS * 4);  // 16 MB

  cast_f2b<<<(L * H) / 256, 256, 0, stream>>>(x, x_b, L * H);

  dim3 tb(32, 8);
  transpose_cast<<<dim3((2 * D) / 32, H / 32), tb, 0, stream>>>(W_in, WinT, H, 2 * D);
  transpose_cast<<<dim3(H / 32, D / 32), tb, 0, stream>>>(W_out, WoutT, D, H);
  transpose_cast<<<dim3(160 / 32, D / 32), tb, 0, stream>>>(W_x, WxT, D, 160);
  transpose_cast<<<dim3(D / 32, R / 32), tb, 0, stream>>>(W_dt, WdtT, R, D);

  // proj = x @ W_in   [L, 2D] fp32
  gemm_bt<false, false><<<dim3((2 * D) / 128, L / 128), 256, 0, stream>>>(
      x_b, H, WinT, H, proj, 2 * D, 2 * D, H);
  // hs = silu(conv(proj[:, :D]))
  conv_silu<<<(L * D) / 256, 256, 0, stream>>>(proj, conv_w, conv_b, hs_f, hs_b);
  // ssm_p = hs @ W_x   [L, 160] fp32
  gemm_bt<false, true><<<dim3(2, L / 128), 256, 0, stream>>>(
      hs_b, D, WxT, D, ssmp, 160, 160, D);
  dtin_cast<<<(L * R) / 256, 256, 0, stream>>>(ssmp, dtin_b);
  // dt_pre = dt_in @ W_dt   [L, D] fp32 (softplus folded into scan phases)
  gemm_bt<false, false><<<dim3(D / 128, L / 128), 256, 0, stream>>>(
      dtin_b, R, WdtT, R, dtbuf, D, D, R);

  // chunked scan
  scan_phase1<<<dim3(D / 256, CCH), 256, 0, stream>>>(
      dtbuf, b_dt, hs_f, ssmp, A_log, sdt, Sbuf);
  scan_phase2<<<(D * NS) / 256, 256, 0, stream>>>(sdt, Sbuf, A_log, Ibuf);
  scan_phase3<<<dim3(D / 256, CCH), 256, 0, stream>>>(
      dtbuf, b_dt, hs_f, ssmp, proj, A_log, D_par, Ibuf, y_b);

  // out = y @ W_out   [L, H] fp32
  gemm_bt<false, false><<<dim3(H / 128, L / 128), 256, 0, stream>>>(
      y_b, D, WoutT, D, outp, H, H, D);
}

// Round 4
// 537.323 us; speedup vs baseline: 3.8168x; 1.2064x over previous
//
#include <hip/hip_runtime.h>
#include <hip/hip_bf16.h>

typedef short short8 __attribute__((ext_vector_type(8)));
typedef float floatx4 __attribute__((ext_vector_type(4)));
using bf16 = __hip_bfloat16;

static constexpr int L = 2048, H = 2048, D = 4096, NS = 16, R = 128, KC = 4;
static constexpr int CCH = 64, TCH = L / CCH;   // 64 chunks x 32 steps
static constexpr int KSP = 16, KCHUNK = 4096 / KSP;  // split-K for ssm_p

__device__ __forceinline__ void g2lds16(const void* g, void* l) {
  __builtin_amdgcn_global_load_lds((const __attribute__((address_space(1))) unsigned int*)g,
                                   (__attribute__((address_space(3))) unsigned int*)l,
                                   16, 0, 0);
}

// ---------------- elementwise fp32 -> bf16 cast ----------------
__global__ void cast_f2b(const float* __restrict__ in, bf16* __restrict__ out, int n) {
  int i = blockIdx.x * 256 + threadIdx.x;
  if (i < n) out[i] = __float2bfloat16(in[i]);
}

// ------------- weight transpose+cast (fp32 [Rr,Cc] -> bf16 [Cc,Rr]) -------------
__global__ void transpose_cast(const float* __restrict__ in, bf16* __restrict__ out,
                               int Rr, int Cc) {
  __shared__ float tile[32][33];
  int c0 = blockIdx.x * 32, r0 = blockIdx.y * 32;
  int tx = threadIdx.x, ty = threadIdx.y;  // 32 x 8
#pragma unroll
  for (int i = 0; i < 32; i += 8)
    tile[ty + i][tx] = in[(size_t)(r0 + ty + i) * Cc + (c0 + tx)];
  __syncthreads();
#pragma unroll
  for (int i = 0; i < 32; i += 8)
    out[(size_t)(c0 + ty + i) * Rr + (r0 + tx)] = __float2bfloat16(tile[tx][ty + i]);
}

// ------- dense bf16 MFMA GEMM (async staging): C[M,N] = A[M,K]*Bt[N,K]^T -------
// m97 structure: 128x128 tile, unpadded 128x32 LDS, global_load_lds width=16.
// All dims must be multiples of the tile (no guards).
__global__ __launch_bounds__(256) void gemm_async(
    const bf16* __restrict__ A, int lda,
    const bf16* __restrict__ Bt, int ldb,
    float* __restrict__ C, int ldc, int K) {
  __shared__ short As[128 * 32];
  __shared__ short Bs[128 * 32];
  const int m0 = blockIdx.y * 128, n0 = blockIdx.x * 128;
  const int tid = threadIdx.x;
  const int lane = tid & 63;
  const int wave = tid >> 6;
  const int wm = (wave >> 1) * 64, wn = (wave & 1) * 64;
  const int lr = lane & 15, kq = lane >> 4;
  // staging geometry: each wave call covers 16 rows; lane -> (row = lane>>2, col8 = (lane&3)*8)
  const int sr = lane >> 2, sc = (lane & 3) * 8;

  const bf16* Ab = A + (size_t)(m0 + wave * 16 + sr) * lda + sc;
  const bf16* Bb = Bt + (size_t)(n0 + wave * 16 + sr) * ldb + sc;
  short* Asw = &As[wave * 16 * 32];
  short* Bsw = &Bs[wave * 16 * 32];

  floatx4 acc[4][4];
#pragma unroll
  for (int i = 0; i < 4; i++)
#pragma unroll
    for (int j = 0; j < 4; j++)
#pragma unroll
      for (int r = 0; r < 4; r++) acc[i][j][r] = 0.f;

  for (int k0 = 0; k0 < K; k0 += 32) {
    __syncthreads();
#pragma unroll
    for (int j = 0; j < 2; j++) {
      g2lds16(Ab + (size_t)j * 64 * lda + k0, Asw + j * 64 * 32);
      g2lds16(Bb + (size_t)j * 64 * ldb + k0, Bsw + j * 64 * 32);
    }
    __syncthreads();
    short8 af[4], bfr[4];
#pragma unroll
    for (int i = 0; i < 4; i++)
      af[i] = *(const short8*)(&As[(wm + i * 16 + lr) * 32 + kq * 8]);
#pragma unroll
    for (int j = 0; j < 4; j++)
      bfr[j] = *(const short8*)(&Bs[(wn + j * 16 + lr) * 32 + kq * 8]);
#pragma unroll
    for (int i = 0; i < 4; i++)
#pragma unroll
      for (int j = 0; j < 4; j++)
        acc[i][j] = __builtin_amdgcn_mfma_f32_16x16x32_bf16(af[i], bfr[j], acc[i][j], 0, 0, 0);
  }

  const int rb = kq * 4;  // C/D: col = lane&15, row = (lane>>4)*4 + reg
#pragma unroll
  for (int i = 0; i < 4; i++)
#pragma unroll
    for (int j = 0; j < 4; j++) {
      int col = n0 + wn + j * 16 + lr;
      int row = m0 + wm + i * 16 + rb;
#pragma unroll
      for (int r = 0; r < 4; r++)
        C[(size_t)(row + r) * ldc + col] = acc[i][j][r];
    }
}

// ------- split-K guarded GEMM for ssm_p: partial[z][M][N] over K-chunk -------
__global__ __launch_bounds__(256) void gemm_splitk(
    const bf16* __restrict__ A, int lda,
    const bf16* __restrict__ Bt, int ldb,
    float* __restrict__ P, int ldc, int N) {
  __shared__ short As[128 * 40];
  __shared__ short Bs[128 * 40];
  const int m0 = blockIdx.y * 128, n0 = blockIdx.x * 128;
  const int kbeg = blockIdx.z * KCHUNK;
  float* C = P + (size_t)blockIdx.z * 2048 * ldc;
  const int tid = threadIdx.x;
  const int lane = tid & 63;
  const int wave = tid >> 6;
  const int wm = (wave >> 1) * 64, wn = (wave & 1) * 64;
  const int lr = lane & 15, kq = lane >> 4;
  const int srow = tid >> 2, scol = (tid & 3) * 8;

  floatx4 acc[4][4];
#pragma unroll
  for (int i = 0; i < 4; i++)
#pragma unroll
    for (int j = 0; j < 4; j++)
#pragma unroll
      for (int r = 0; r < 4; r++) acc[i][j][r] = 0.f;

  for (int k0 = kbeg; k0 < kbeg + KCHUNK; k0 += 32) {
    __syncthreads();
#pragma unroll
    for (int h = 0; h < 2; h++) {
      int r = srow + h * 64;
      short8 va = *(const short8*)((const short*)A + (size_t)(m0 + r) * lda + k0 + scol);
      *(short8*)(&As[r * 40 + scol]) = va;
    }
#pragma unroll
    for (int h = 0; h < 2; h++) {
      int r = srow + h * 64;
      short8 vb;
      if ((n0 + r) < N) {
        vb = *(const short8*)((const short*)Bt + (size_t)(n0 + r) * ldb + k0 + scol);
      } else {
#pragma unroll
        for (int q = 0; q < 8; q++) vb[q] = 0;
      }
      *(short8*)(&Bs[r * 40 + scol]) = vb;
    }
    __syncthreads();
    short8 af[4], bfr[4];
#pragma unroll
    for (int i = 0; i < 4; i++)
      af[i] = *(const short8*)(&As[(wm + i * 16 + lr) * 40 + kq * 8]);
#pragma unroll
    for (int j = 0; j < 4; j++)
      bfr[j] = *(const short8*)(&Bs[(wn + j * 16 + lr) * 40 + kq * 8]);
#pragma unroll
    for (int i = 0; i < 4; i++)
#pragma unroll
      for (int j = 0; j < 4; j++)
        acc[i][j] = __builtin_amdgcn_mfma_f32_16x16x32_bf16(af[i], bfr[j], acc[i][j], 0, 0, 0);
  }

  const int rb = kq * 4;
#pragma unroll
  for (int i = 0; i < 4; i++)
#pragma unroll
    for (int j = 0; j < 4; j++) {
      int col = n0 + wn + j * 16 + lr;
      if (col >= N) continue;
      int row = m0 + wm + i * 16 + rb;
#pragma unroll
      for (int r = 0; r < 4; r++)
        C[(size_t)(row + r) * ldc + col] = acc[i][j][r];
    }
}

// ------- split-K reduce + fused dt_in bf16 cast -------
__global__ void splitk_reduce(const float* __restrict__ P, float* __restrict__ ssmp,
                              bf16* __restrict__ dtin) {
  int idx = blockIdx.x * 256 + threadIdx.x;  // t*160 + c
  float s = 0.f;
#pragma unroll
  for (int z = 0; z < KSP; z++) s += P[(size_t)z * 2048 * 160 + idx];
  ssmp[idx] = s;
  int t = idx / 160, c = idx - t * 160;
  if (c < R) dtin[t * R + c] = __float2bfloat16(s);
}

// ---------------- causal depthwise conv (K=4) + bias + SiLU ----------------
__global__ void conv_silu(const float* __restrict__ proj,
                          const float* __restrict__ conv_w, const float* __restrict__ conv_b,
                          bf16* __restrict__ hs_b) {
  int idx = blockIdx.x * 256 + threadIdx.x;  // t*D + d
  int d = idx & (D - 1), t = idx >> 12;
  float acc = conv_b[d];
#pragma unroll
  for (int k = 0; k < KC; k++) {
    int tt = t + k - (KC - 1);
    if (tt >= 0) acc += proj[(size_t)tt * (2 * D) + d] * conv_w[k * D + d];
  }
  float s = acc / (1.f + __expf(-acc));
  hs_b[idx] = __float2bfloat16(s);
}

__device__ __forceinline__ float softplusf(float v) {
  return (v > 20.f) ? v : log1pf(__expf(v));
}

// ---------------- scan phase 1: per-chunk local scan ----------------
__global__ __launch_bounds__(256) void scan_phase1(
    const float* __restrict__ dtraw, const float* __restrict__ b_dt,
    const bf16* __restrict__ hs_b, const float* __restrict__ ssmp,
    const float* __restrict__ A_log,
    float* __restrict__ sdt_out, float* __restrict__ S_out) {
  const int d = blockIdx.x * 256 + threadIdx.x;
  const int c = blockIdx.y;
  float An[NS];
#pragma unroll
  for (int n = 0; n < NS; n++) An[n] = -__expf(A_log[d * NS + n]);
  const float bdt = b_dt[d];
  float s[NS];
#pragma unroll
  for (int n = 0; n < NS; n++) s[n] = 0.f;
  float sdt = 0.f;
  const int t0 = c * TCH;
#pragma unroll 2
  for (int t = t0; t < t0 + TCH; t++) {
    float dtv = softplusf(dtraw[(size_t)t * D + d] + bdt);
    float hsv = __bfloat162float(hs_b[(size_t)t * D + d]);
    sdt += dtv;
    float u = dtv * hsv;
    const float* Bp = ssmp + (size_t)t * 160 + 128;
#pragma unroll
    for (int n = 0; n < NS; n++) {
      float dA = __expf(An[n] * dtv);
      s[n] = dA * s[n] + Bp[n] * u;
    }
  }
  sdt_out[(size_t)c * D + d] = sdt;
  float* Sp = S_out + ((size_t)c * D + d) * NS;
#pragma unroll
  for (int n = 0; n < NS; n += 4)
    *(floatx4*)(Sp + n) = *(floatx4*)(s + n);
}

// ---------------- scan phase 2: sequential combine over chunks ----------------
__global__ __launch_bounds__(256) void scan_phase2(
    const float* __restrict__ sdt, const float* __restrict__ S,
    const float* __restrict__ A_log, float* __restrict__ I) {
  int g = blockIdx.x * 256 + threadIdx.x;  // d*16 + n
  int d = g >> 4;
  float An = -__expf(A_log[g]);
  float cur = 0.f;
  for (int c = 0; c < CCH; c++) {
    I[(size_t)c * D * NS + g] = cur;
    cur = __expf(An * sdt[(size_t)c * D + d]) * cur + S[(size_t)c * D * NS + g];
  }
}

// ---------------- scan phase 3: seeded per-chunk scan + fused epilogue ----------------
__global__ __launch_bounds__(256) void scan_phase3(
    const float* __restrict__ dtraw, const float* __restrict__ b_dt,
    const bf16* __restrict__ hs_b, const float* __restrict__ ssmp,
    const float* __restrict__ proj, const float* __restrict__ A_log,
    const float* __restrict__ D_param, const float* __restrict__ I,
    bf16* __restrict__ y_b) {
  const int d = blockIdx.x * 256 + threadIdx.x;
  const int c = blockIdx.y;
  float An[NS];
#pragma unroll
  for (int n = 0; n < NS; n++) An[n] = -__expf(A_log[d * NS + n]);
  const float bdt = b_dt[d];
  const float Dp = D_param[d];
  float s[NS];
  const float* Ip = I + ((size_t)c * D + d) * NS;
#pragma unroll
  for (int n = 0; n < NS; n += 4)
    *(floatx4*)(s + n) = *(const floatx4*)(Ip + n);
  const int t0 = c * TCH;
#pragma unroll 2
  for (int t = t0; t < t0 + TCH; t++) {
    float dtv = softplusf(dtraw[(size_t)t * D + d] + bdt);
    float hsv = __bfloat162float(hs_b[(size_t)t * D + d]);
    float u = dtv * hsv;
    const float* Bp = ssmp + (size_t)t * 160 + 128;
    const float* Cp = ssmp + (size_t)t * 160 + 144;
    float y = 0.f;
#pragma unroll
    for (int n = 0; n < NS; n++) {
      float dA = __expf(An[n] * dtv);
      s[n] = dA * s[n] + Bp[n] * u;
      y += s[n] * Cp[n];
    }
    float gv = proj[(size_t)t * (2 * D) + D + d];
    float yv = (y + hsv * Dp) * (gv / (1.f + __expf(-gv)));
    y_b[(size_t)t * D + d] = __float2bfloat16(yv);
  }
}

extern "C" void kernel_launch(void* const* d_in, const int* in_sizes, int n_in,
                              void* d_out, int out_size, void* d_ws, size_t ws_size,
                              hipStream_t stream) {
  const float* x      = (const float*)d_in[0];
  const float* W_in   = (const float*)d_in[1];
  const float* conv_w = (const float*)d_in[2];
  const float* conv_b = (const float*)d_in[3];
  const float* W_x    = (const float*)d_in[4];
  const float* W_dt   = (const float*)d_in[5];
  const float* b_dt   = (const float*)d_in[6];
  const float* A_log  = (const float*)d_in[7];
  const float* D_par  = (const float*)d_in[8];
  const float* W_out  = (const float*)d_in[9];
  float* outp = (float*)d_out;

  char* ws = (char*)d_ws;
  size_t off = 0;
  auto alloc = [&](size_t bytes) {
    char* p = ws + off;
    off += (bytes + 255) & ~(size_t)255;
    return (void*)p;
  };
  float* proj   = (float*)alloc((size_t)L * 2 * D * 4);       // 64 MB
  bf16*  hs_b   = (bf16*) alloc((size_t)L * D * 2);           // 16 MB
  float* ssmp   = (float*)alloc((size_t)L * 160 * 4);         // 1.25 MB
  bf16*  dtin_b = (bf16*) alloc((size_t)L * R * 2);           // 0.5 MB
  float* dtbuf  = (float*)alloc((size_t)L * D * 4);           // 32 MB
  bf16*  y_b    = (bf16*) alloc((size_t)L * D * 2);           // 16 MB
  bf16*  x_b    = (bf16*) alloc((size_t)L * H * 2);           // 8 MB
  bf16*  WinT   = (bf16*) alloc((size_t)2 * D * H * 2);       // 32 MB
  bf16*  WoutT  = (bf16*) alloc((size_t)H * D * 2);           // 16 MB
  bf16*  WxT    = (bf16*) alloc((size_t)160 * D * 2);         // 1.25 MB
  bf16*  WdtT   = (bf16*) alloc((size_t)D * R * 2);           // 1 MB
  float* sdt    = (float*)alloc((size_t)CCH * D * 4);         // 1 MB
  float* Sbuf   = (float*)alloc((size_t)CCH * D * NS * 4);    // 16 MB
  float* Ibuf   = (float*)alloc((size_t)CCH * D * NS * 4);    // 16 MB
  float* part   = (float*)alloc((size_t)KSP * L * 160 * 4);   // 20 MB

  cast_f2b<<<(L * H) / 256, 256, 0, stream>>>(x, x_b, L * H);

  dim3 tb(32, 8);
  transpose_cast<<<dim3((2 * D) / 32, H / 32), tb, 0, stream>>>(W_in, WinT, H, 2 * D);
  transpose_cast<<<dim3(H / 32, D / 32), tb, 0, stream>>>(W_out, WoutT, D, H);
  transpose_cast<<<dim3(160 / 32, D / 32), tb, 0, stream>>>(W_x, WxT, D, 160);
  transpose_cast<<<dim3(D / 32, R / 32), tb, 0, stream>>>(W_dt, WdtT, R, D);

  // proj = x @ W_in   [L, 2D] fp32
  gemm_async<<<dim3((2 * D) / 128, L / 128), 256, 0, stream>>>(
      x_b, H, WinT, H, proj, 2 * D, H);
  // hs = silu(conv(proj[:, :D])) -> bf16
  conv_silu<<<(L * D) / 256, 256, 0, stream>>>(proj, conv_w, conv_b, hs_b);
  // ssm_p = hs @ W_x  [L, 160] via split-K partials + reduce (fused dtin cast)
  gemm_splitk<<<dim3(2, L / 128, KSP), 256, 0, stream>>>(
      hs_b, D, WxT, D, part, 160, 160);
  splitk_reduce<<<(L * 160) / 256, 256, 0, stream>>>(part, ssmp, dtin_b);
  // dt_pre = dt_in @ W_dt  [L, D] fp32 (softplus folded into scan)
  gemm_async<<<dim3(D / 128, L / 128), 256, 0, stream>>>(
      dtin_b, R, WdtT, R, dtbuf, D, R);

  // chunked scan
  scan_phase1<<<dim3(D / 256, CCH), 256, 0, stream>>>(
      dtbuf, b_dt, hs_b, ssmp, A_log, sdt, Sbuf);
  scan_phase2<<<(D * NS) / 256, 256, 0, stream>>>(sdt, Sbuf, A_log, Ibuf);
  scan_phase3<<<dim3(D / 256, CCH), 256, 0, stream>>>(
      dtbuf, b_dt, hs_b, ssmp, proj, A_log, D_par, Ibuf, y_b);

  // out = y @ W_out   [L, H] fp32
  gemm_async<<<dim3(H / 128, L / 128), 256, 0, stream>>>(
      y_b, D, WoutT, D, outp, H, D);
}